// Round 1
// baseline (1030.011 us; speedup 1.0000x reference)
//
#include <hip/hip_runtime.h>

#define B_TOT   20000
#define M_TOT   49
#define IN_DIM  128
#define OUT_DIM 128
#define TILE_B  128

typedef short v8s __attribute__((ext_vector_type(8)));
typedef float v4f __attribute__((ext_vector_type(4)));

__device__ __forceinline__ short f2bf(float x) {
    union { float f; unsigned int u; } c; c.f = x;
    unsigned int r = c.u + 0x7FFFu + ((c.u >> 16) & 1u);   // RNE
    return (short)(r >> 16);
}

// One block: one m (one l), one 128-row b-tile. 256 threads = 4 waves.
// Each wave computes a 64x64 quadrant of the 128x128 output tile.
__global__ void so3_linear_kernel(const float* __restrict__ inp,
                                  const float* __restrict__ wgt,
                                  const float* __restrict__ bias,
                                  float* __restrict__ out) {
    // LDS: bf16 A-tile and W-tile, 16B-chunk XOR swizzle (chunk ^= row&15)
    __shared__ __align__(16) short As[TILE_B][IN_DIM];    // 32 KB
    __shared__ __align__(16) short Ws[OUT_DIM][IN_DIM];   // 32 KB

    const int tid  = threadIdx.x;
    const int m    = blockIdx.y;
    const int b0   = blockIdx.x * TILE_B;

    int l = 0;
    while ((l + 1) * (l + 1) <= m) ++l;   // l = floor(sqrt(m))

    // ---- stage A tile: 128 rows x 128 fp32 -> bf16 LDS ----
    const float4* inp4 = (const float4*)inp;
    #pragma unroll
    for (int it = 0; it < 16; ++it) {
        int f  = it * 256 + tid;          // 0..4095 float4 slots
        int r  = f >> 5;                  // LDS row 0..127
        int c4 = f & 31;                  // float4 col 0..31
        int gb = b0 + r;
        float4 v = make_float4(0.f, 0.f, 0.f, 0.f);
        if (gb < B_TOT)
            v = inp4[((size_t)gb * M_TOT + m) * (IN_DIM / 4) + c4];
        short4 s;
        s.x = f2bf(v.x); s.y = f2bf(v.y); s.z = f2bf(v.z); s.w = f2bf(v.w);
        int sc = (((c4 >> 1) ^ (r & 15)) << 3) + ((c4 & 1) << 2);
        *(short4*)&As[r][sc] = s;
    }

    // ---- stage W[l]: 128 x 128 fp32 -> bf16 LDS ----
    const float4* wp4 = (const float4*)(wgt + (size_t)l * OUT_DIM * IN_DIM);
    #pragma unroll
    for (int it = 0; it < 16; ++it) {
        int f  = it * 256 + tid;
        int r  = f >> 5;
        int c4 = f & 31;
        float4 v = wp4[r * (IN_DIM / 4) + c4];
        short4 s;
        s.x = f2bf(v.x); s.y = f2bf(v.y); s.z = f2bf(v.z); s.w = f2bf(v.w);
        int sc = (((c4 >> 1) ^ (r & 15)) << 3) + ((c4 & 1) << 2);
        *(short4*)&Ws[r][sc] = s;
    }

    __syncthreads();

    // ---- MFMA: wave quadrant 64x64, 4x4 tiles of 16x16, K=128 ----
    const int wave = tid >> 6;
    const int lane = tid & 63;
    const int lr   = lane & 15;
    const int quad = lane >> 4;
    const int wrow = (wave >> 1) * 64;
    const int wcol = (wave & 1) * 64;

    v4f acc[4][4];
    #pragma unroll
    for (int i = 0; i < 4; ++i)
        #pragma unroll
        for (int j = 0; j < 4; ++j)
            acc[i][j] = (v4f)(0.f);

    #pragma unroll
    for (int kk = 0; kk < 4; ++kk) {
        const int chunk = kk * 4 + quad;             // 16B-chunk index along K
        const int sc    = ((chunk ^ lr) << 3);       // swizzled short offset
        v8s af[4], bf[4];
        #pragma unroll
        for (int i = 0; i < 4; ++i)
            af[i] = *(const v8s*)&As[wrow + i * 16 + lr][sc];
        #pragma unroll
        for (int j = 0; j < 4; ++j)
            bf[j] = *(const v8s*)&Ws[wcol + j * 16 + lr][sc];
        #pragma unroll
        for (int i = 0; i < 4; ++i)
            #pragma unroll
            for (int j = 0; j < 4; ++j)
                acc[i][j] = __builtin_amdgcn_mfma_f32_16x16x32_bf16(
                                af[i], bf[j], acc[i][j], 0, 0, 0);
    }

    // ---- epilogue: C layout col=lane&15, row=quad*4+reg (m89/m91) ----
    #pragma unroll
    for (int i = 0; i < 4; ++i) {
        const int rowbase = wrow + i * 16 + quad * 4;
        #pragma unroll
        for (int j = 0; j < 4; ++j) {
            const int col = wcol + j * 16 + lr;
            float bv = 0.f;
            if (m == 0) bv = bias[col];
            #pragma unroll
            for (int r = 0; r < 4; ++r) {
                const int gb = b0 + rowbase + r;
                if (gb < B_TOT) {
                    size_t off = ((size_t)gb * M_TOT + m) * OUT_DIM + col;
                    out[off] = acc[i][j][r] + bv;
                }
            }
        }
    }
}

extern "C" void kernel_launch(void* const* d_in, const int* in_sizes, int n_in,
                              void* d_out, int out_size, void* d_ws, size_t ws_size,
                              hipStream_t stream) {
    const float* inp  = (const float*)d_in[0];   // [20000, 49, 128] f32
    const float* wgt  = (const float*)d_in[1];   // [7, 128, 128]   f32
    const float* bias = (const float*)d_in[2];   // [128]           f32
    float* out = (float*)d_out;                  // [20000, 49, 128] f32

    dim3 grid((B_TOT + TILE_B - 1) / TILE_B, M_TOT);  // 157 x 49
    dim3 block(256);
    so3_linear_kernel<<<grid, block, 0, stream>>>(inp, wgt, bias, out);
}